// Round 5
// baseline (1019.756 us; speedup 1.0000x reference)
//
#include <hip/hip_runtime.h>
#include <hip/hip_cooperative_groups.h>
#include <hip/hip_bf16.h>

namespace cg = cooperative_groups;

// LightGCN forward on MI355X — single cooperative kernel, pull-based CSR
// gather with bf16 operand tables. Node order: users [0,U), items [U,U+I).
// out = (x0 + A x0 + A A x0) / 3, A = D^-1/2 Adj D^-1/2 (no self loops).
// Phases separated by grid.sync(); 1024 blocks x 256 thr co-resident
// (launch_bounds(256,4) => 4 blocks/CU * 256 CUs).

#define DIM 128
#define NBLOCKS 1024
#define NTHR 256

struct __align__(8) Pair { int s; float w; };

// round-to-nearest-even f32 -> bf16 bits
__device__ __forceinline__ ushort f2bf(float f) {
    uint u = __float_as_uint(f);
    u += 0x7fffu + ((u >> 16) & 1u);
    return (ushort)(u >> 16);
}
__device__ __forceinline__ float bflo(uint u) { return __uint_as_float(u << 16); }
__device__ __forceinline__ float bfhi(uint u) { return __uint_as_float(u & 0xffff0000u); }

// block-level inclusive scan, blockDim = 256 (4 waves)
__device__ __forceinline__ int block_incl_scan(int v, int* lds) {
    int lane = threadIdx.x & 63;
    int wid = threadIdx.x >> 6;
    #pragma unroll
    for (int off = 1; off < 64; off <<= 1) {
        int t = __shfl_up(v, off);
        if (lane >= off) v += t;
    }
    if (lane == 63) lds[wid] = v;
    __syncthreads();
    if (threadIdx.x == 0) {
        int s = 0;
        #pragma unroll
        for (int w = 0; w < 4; w++) { int t = lds[w]; lds[w] = s; s += t; }
    }
    __syncthreads();
    return v + lds[wid];
}

__global__ __launch_bounds__(256, 4) void lightgcn_all(
        const float* __restrict__ xu, const float* __restrict__ xi,
        const int* __restrict__ ui_src, const int* __restrict__ ui_dst,
        const int* __restrict__ iu_src, const int* __restrict__ iu_dst,
        int E, int U, int I,
        int* __restrict__ deg, int* __restrict__ cursor,
        int* __restrict__ row_ptr, int* __restrict__ partials,
        float* __restrict__ dinv, Pair* __restrict__ pairs,
        ushort* __restrict__ xb, ushort* __restrict__ Tb,
        float* __restrict__ out) {
    cg::grid_group grid = cg::this_grid();
    __shared__ int lds[16];
    __shared__ int runsh;

    const int N = U + I;
    const long tid = (long)blockIdx.x * blockDim.x + threadIdx.x;
    const long nth = (long)gridDim.x * blockDim.x;
    const long total = (long)N * DIM;
    const long uelems = (long)U * DIM;

    // ---- P0: zero degrees ----
    for (long i = tid; i < N; i += nth) deg[i] = 0;
    grid.sync();

    // ---- P1: degree histogram + x0 -> bf16 convert (independent work) ----
    for (long e = tid; e < E; e += nth) {
        atomicAdd(&deg[ui_dst[e] + U], 1);
        atomicAdd(&deg[iu_dst[e]], 1);
    }
    for (long u = tid; u < (total >> 3); u += nth) {
        long i8 = u << 3;
        const float* src = (i8 < uelems) ? (xu + i8) : (xi + (i8 - uelems));
        float4 a = *reinterpret_cast<const float4*>(src);
        float4 b = *reinterpret_cast<const float4*>(src + 4);
        uint4 q;
        q.x = ((uint)f2bf(a.y) << 16) | f2bf(a.x);
        q.y = ((uint)f2bf(a.w) << 16) | f2bf(a.z);
        q.z = ((uint)f2bf(b.y) << 16) | f2bf(b.x);
        q.w = ((uint)f2bf(b.w) << 16) | f2bf(b.z);
        *reinterpret_cast<uint4*>(xb + i8) = q;
    }
    grid.sync();

    // ---- P2: per-chunk (256-elem) exclusive scan; chunk totals -> partials ----
    const int nchunk = (N + 255) >> 8;
    for (int c = blockIdx.x; c < nchunk; c += gridDim.x) {
        int i = (c << 8) + threadIdx.x;
        int v = (i < N) ? deg[i] : 0;
        int incl = block_incl_scan(v, lds);
        if (i < N) row_ptr[i] = incl - v;          // exclusive within chunk
        if (threadIdx.x == 255) partials[c] = incl;
        __syncthreads();
    }
    grid.sync();

    // ---- P3: top-level exclusive scan of chunk totals (block 0 only) ----
    if (blockIdx.x == 0) {
        if (threadIdx.x == 0) runsh = 0;
        __syncthreads();
        for (int base = 0; base < nchunk; base += 256) {
            int idx = base + threadIdx.x;
            int v = (idx < nchunk) ? partials[idx] : 0;
            int incl = block_incl_scan(v, lds);
            int run = runsh;
            __syncthreads();
            if (idx < nchunk) partials[idx] = incl - v + run;
            if (threadIdx.x == 255) runsh = run + incl;
            __syncthreads();
        }
        if (threadIdx.x == 0) row_ptr[N] = runsh;
    }
    grid.sync();

    // ---- P4: add-back -> row_ptr/cursor; dinv ----
    for (long i = tid; i < N; i += nth) {
        int excl = row_ptr[i] + partials[i >> 8];
        row_ptr[i] = excl;
        cursor[i] = excl;
        int d = deg[i];
        dinv[i] = (d > 0) ? rsqrtf((float)d) : 0.0f;
    }
    grid.sync();

    // ---- P5: CSR fill with (src, dinv[src]) pairs ----
    for (long e = tid; e < E; e += nth) {
        int s = ui_src[e], d0 = ui_dst[e] + U;
        int pos = atomicAdd(&cursor[d0], 1);
        pairs[pos] = {s, dinv[s]};
        s = iu_src[e] + U; d0 = iu_dst[e];
        pos = atomicAdd(&cursor[d0], 1);
        pairs[pos] = {s, dinv[s]};
    }
    grid.sync();

    // ---- P6: gather layer 1: Tb[d] = bf16( dinv[d] * sum_s xb[s]*w ) ----
    // 16 lanes per node, 16B (8 bf16) per lane, 2-way unrolled.
    const long lanes = (long)N * 16;
    for (long u = tid; u < lanes; u += nth) {
        int lane = (int)(u & 15);
        long node = u >> 4;
        int start = row_ptr[node], end = row_ptr[node + 1];
        float a0 = 0.f, a1 = 0.f, a2 = 0.f, a3 = 0.f,
              a4 = 0.f, a5 = 0.f, a6 = 0.f, a7 = 0.f;
        int j = start;
        for (; j + 2 <= end; j += 2) {
            Pair p0 = pairs[j], p1 = pairs[j + 1];
            uint4 q0 = *reinterpret_cast<const uint4*>(xb + (size_t)p0.s * DIM + lane * 8);
            uint4 q1 = *reinterpret_cast<const uint4*>(xb + (size_t)p1.s * DIM + lane * 8);
            a0 = fmaf(bflo(q0.x), p0.w, fmaf(bflo(q1.x), p1.w, a0));
            a1 = fmaf(bfhi(q0.x), p0.w, fmaf(bfhi(q1.x), p1.w, a1));
            a2 = fmaf(bflo(q0.y), p0.w, fmaf(bflo(q1.y), p1.w, a2));
            a3 = fmaf(bfhi(q0.y), p0.w, fmaf(bfhi(q1.y), p1.w, a3));
            a4 = fmaf(bflo(q0.z), p0.w, fmaf(bflo(q1.z), p1.w, a4));
            a5 = fmaf(bfhi(q0.z), p0.w, fmaf(bfhi(q1.z), p1.w, a5));
            a6 = fmaf(bflo(q0.w), p0.w, fmaf(bflo(q1.w), p1.w, a6));
            a7 = fmaf(bfhi(q0.w), p0.w, fmaf(bfhi(q1.w), p1.w, a7));
        }
        if (j < end) {
            Pair p = pairs[j];
            uint4 q = *reinterpret_cast<const uint4*>(xb + (size_t)p.s * DIM + lane * 8);
            a0 = fmaf(bflo(q.x), p.w, a0);
            a1 = fmaf(bfhi(q.x), p.w, a1);
            a2 = fmaf(bflo(q.y), p.w, a2);
            a3 = fmaf(bfhi(q.y), p.w, a3);
            a4 = fmaf(bflo(q.z), p.w, a4);
            a5 = fmaf(bfhi(q.z), p.w, a5);
            a6 = fmaf(bflo(q.w), p.w, a6);
            a7 = fmaf(bfhi(q.w), p.w, a7);
        }
        float dd = dinv[node];
        uint4 r;
        r.x = ((uint)f2bf(a1 * dd) << 16) | f2bf(a0 * dd);
        r.y = ((uint)f2bf(a3 * dd) << 16) | f2bf(a2 * dd);
        r.z = ((uint)f2bf(a5 * dd) << 16) | f2bf(a4 * dd);
        r.w = ((uint)f2bf(a7 * dd) << 16) | f2bf(a6 * dd);
        *reinterpret_cast<uint4*>(Tb + (size_t)node * DIM + lane * 8) = r;
    }
    grid.sync();

    // ---- P7: gather layer 2 + combine (fp32 out; x0 term from xb) ----
    for (long u = tid; u < lanes; u += nth) {
        int lane = (int)(u & 15);
        long node = u >> 4;
        int start = row_ptr[node], end = row_ptr[node + 1];
        float a0 = 0.f, a1 = 0.f, a2 = 0.f, a3 = 0.f,
              a4 = 0.f, a5 = 0.f, a6 = 0.f, a7 = 0.f;
        int j = start;
        for (; j + 2 <= end; j += 2) {
            Pair p0 = pairs[j], p1 = pairs[j + 1];
            uint4 q0 = *reinterpret_cast<const uint4*>(Tb + (size_t)p0.s * DIM + lane * 8);
            uint4 q1 = *reinterpret_cast<const uint4*>(Tb + (size_t)p1.s * DIM + lane * 8);
            a0 = fmaf(bflo(q0.x), p0.w, fmaf(bflo(q1.x), p1.w, a0));
            a1 = fmaf(bfhi(q0.x), p0.w, fmaf(bfhi(q1.x), p1.w, a1));
            a2 = fmaf(bflo(q0.y), p0.w, fmaf(bflo(q1.y), p1.w, a2));
            a3 = fmaf(bfhi(q0.y), p0.w, fmaf(bfhi(q1.y), p1.w, a3));
            a4 = fmaf(bflo(q0.z), p0.w, fmaf(bflo(q1.z), p1.w, a4));
            a5 = fmaf(bfhi(q0.z), p0.w, fmaf(bfhi(q1.z), p1.w, a5));
            a6 = fmaf(bflo(q0.w), p0.w, fmaf(bflo(q1.w), p1.w, a6));
            a7 = fmaf(bfhi(q0.w), p0.w, fmaf(bfhi(q1.w), p1.w, a7));
        }
        if (j < end) {
            Pair p = pairs[j];
            uint4 q = *reinterpret_cast<const uint4*>(Tb + (size_t)p.s * DIM + lane * 8);
            a0 = fmaf(bflo(q.x), p.w, a0);
            a1 = fmaf(bfhi(q.x), p.w, a1);
            a2 = fmaf(bflo(q.y), p.w, a2);
            a3 = fmaf(bfhi(q.y), p.w, a3);
            a4 = fmaf(bflo(q.z), p.w, a4);
            a5 = fmaf(bfhi(q.z), p.w, a5);
            a6 = fmaf(bflo(q.w), p.w, a6);
            a7 = fmaf(bfhi(q.w), p.w, a7);
        }
        float dd = dinv[node];
        size_t off = (size_t)node * DIM + lane * 8;
        uint4 tq = *reinterpret_cast<const uint4*>(Tb + off);
        uint4 xq = *reinterpret_cast<const uint4*>(xb + off);
        const float k = 1.0f / 3.0f;
        float4 r0, r1;
        r0.x = (bflo(xq.x) + bflo(tq.x) + a0 * dd) * k;
        r0.y = (bfhi(xq.x) + bfhi(tq.x) + a1 * dd) * k;
        r0.z = (bflo(xq.y) + bflo(tq.y) + a2 * dd) * k;
        r0.w = (bfhi(xq.y) + bfhi(tq.y) + a3 * dd) * k;
        r1.x = (bflo(xq.z) + bflo(tq.z) + a4 * dd) * k;
        r1.y = (bfhi(xq.z) + bfhi(tq.z) + a5 * dd) * k;
        r1.z = (bflo(xq.w) + bflo(tq.w) + a6 * dd) * k;
        r1.w = (bfhi(xq.w) + bfhi(tq.w) + a7 * dd) * k;
        *reinterpret_cast<float4*>(out + off) = r0;
        *reinterpret_cast<float4*>(out + off + 4) = r1;
    }
}

extern "C" void kernel_launch(void* const* d_in, const int* in_sizes, int n_in,
                              void* d_out, int out_size, void* d_ws, size_t ws_size,
                              hipStream_t stream) {
    const float* xu = (const float*)d_in[0];
    const float* xi = (const float*)d_in[1];
    const int* ui_src = (const int*)d_in[2];
    const int* ui_dst = (const int*)d_in[3];
    const int* iu_src = (const int*)d_in[4];
    const int* iu_dst = (const int*)d_in[5];

    int E = in_sizes[2];
    int U = in_sizes[0] / DIM;
    int I = in_sizes[1] / DIM;
    const int N = U + I;
    const int twoE = 2 * E;
    const long total = (long)N * DIM;

    float* out = (float*)d_out;

    // ws layout
    char* ws = (char*)d_ws;
    size_t off = 0;
    int* deg = (int*)(ws + off); off += (size_t)N * 4;
    int* cursor = (int*)(ws + off); off += (size_t)N * 4;
    int* row_ptr = (int*)(ws + off); off += (size_t)(N + 1) * 4;
    int* partials = (int*)(ws + off); off += 1024 * 4;
    float* dinv = (float*)(ws + off); off += (size_t)N * 4;
    off = (off + 7) & ~(size_t)7;
    Pair* pairs = (Pair*)(ws + off); off += (size_t)twoE * 8;
    off = (off + 511) & ~(size_t)511;
    ushort* xb = (ushort*)(ws + off); off += (size_t)total * 2;
    off = (off + 511) & ~(size_t)511;
    ushort* Tb = (ushort*)(ws + off);

    void* args[] = {
        (void*)&xu, (void*)&xi,
        (void*)&ui_src, (void*)&ui_dst, (void*)&iu_src, (void*)&iu_dst,
        (void*)&E, (void*)&U, (void*)&I,
        (void*)&deg, (void*)&cursor, (void*)&row_ptr, (void*)&partials,
        (void*)&dinv, (void*)&pairs, (void*)&xb, (void*)&Tb, (void*)&out
    };
    hipLaunchCooperativeKernel((void*)lightgcn_all, dim3(NBLOCKS), dim3(NTHR),
                               args, 0, stream);
}